// Round 13
// baseline (1129.042 us; speedup 1.0000x reference)
//
#include <hip/hip_runtime.h>
#include <hip/hip_bf16.h>
#include <stdint.h>

#define N_NODES 100000
#define MT      782          // 128-row tiles (k3)
#define NS256   391          // 256-row stripes (k1,k2)
#define MPAD    (MT*128)     // 100096 = 391*256
#define IN_DIM  2048
#define HID     512
#define OUTD    128
#define NG      512
#define LOG2F_  0.69314718055994531f

typedef __attribute__((ext_vector_type(4))) float f32x4;
typedef __attribute__((ext_vector_type(8))) short bf16x8;

typedef const __attribute__((address_space(1))) unsigned int gas_u32;
typedef __attribute__((address_space(3))) unsigned int las_u32;

__device__ __forceinline__ void gload_lds16(const void* g, void* lds) {
  __builtin_amdgcn_global_load_lds((gas_u32*)g, (las_u32*)lds, 16, 0, 0);
}

__device__ __forceinline__ short f2bf(float f) {   // manual RNE
  unsigned u = __builtin_bit_cast(unsigned, f);
  u = (u + 0x7fffu + ((u >> 16) & 1u)) >> 16;
  return (short)u;
}
__device__ __forceinline__ short f2bf_hw(float f) {
  __hip_bfloat16 h = __float2bfloat16(f);
  return __builtin_bit_cast(short, h);
}
__device__ __forceinline__ float bf2f(short s) {
  unsigned u = ((unsigned)(unsigned short)s) << 16;
  return __builtin_bit_cast(float, u);
}

__device__ __forceinline__ f32x4 mfma16(bf16x8 a, bf16x8 b, f32x4 c) {
  return __builtin_amdgcn_mfma_f32_16x16x32_bf16(a, b, c, 0, 0, 0);
}

// ---------------- prep ---------------------------------------------------------
// wcatS: k-slot global layout [k/8][n(640)][e=k%8]; w2tS same (n=512).
// w3t: row-major [n][k].  gencb: row-major [g][k].
__global__ void kprep(const float* __restrict__ W1, const float* __restrict__ Wj,
                      const float* __restrict__ W2, const float* __restrict__ W3,
                      const float* __restrict__ ge,
                      short* __restrict__ wcatS, short* __restrict__ w2tS,
                      short* __restrict__ w3t, short* __restrict__ gencb) {
  const int S1 = 640 * 2048, S2 = 512 * 512, S3 = 128 * 512, S4 = 512 * 128;
  int t = blockIdx.x * 256 + threadIdx.x;
  if (t < S1) {
    int e = t & 7, rest = t >> 3;
    int n = rest % 640, kb = rest / 640;
    int k = kb * 8 + e;
    float v = (n < 512) ? W1[(size_t)k * 512 + n] : Wj[(size_t)k * 128 + (n - 512)];
    wcatS[t] = f2bf(v);
  } else {
    t -= S1;
    if (t < S2) {
      int e = t & 7, rest = t >> 3;
      int n = rest & 511, kb = rest >> 9;
      int k = kb * 8 + e;
      w2tS[t] = f2bf(W2[(size_t)k * 512 + n]);
    } else {
      t -= S2;
      if (t < S3) {
        int n = t >> 9, k = t & 511;
        w3t[t] = f2bf(W3[(size_t)k * 128 + n]);
      } else {
        t -= S3;
        if (t < S4) gencb[t] = f2bf(ge[t]);
      }
    }
  }
}

// ---- K1: 256x128 tile, 512 thr / 8 waves (4Mw x 2Nw, wave 64x64, acc 64).
// Halves LDS-bytes/FLOP and L2-bytes/FLOP vs the 128x128 structure (the
// measured co-saturated walls). R12 engine: counted vmcnt (never 0 mid-loop),
// raw s_barrier, k-slot LDS (conflict-free), A global->reg 2 steps ahead ->
// cvt -> single-buf As; B dbuf via gload_lds from L2-resident wcatS.
// Grid: bid = r*40 + nt*8 + x, stripe s = r*8+x -> 5 nt-siblings on same XCD.
__global__ __launch_bounds__(512, 4) void k1(
    const float* __restrict__ feat, const short* __restrict__ wcatS,
    const float* __restrict__ b1, const float* __restrict__ b3,
    const float* __restrict__ bj,
    short* __restrict__ h1, short* __restrict__ jmp) {
  __shared__ __align__(16) short As[4 * 256 * 8];      // [ks][row][8] 16KB single
  __shared__ __align__(16) short Bs[2][4 * 128 * 8];   // dbuf 8KB each
  const int tid = threadIdx.x;
  const int lane = tid & 63, w = tid >> 6;
  const int mw = w >> 1, nw = w & 1;
  const int l16 = lane & 15, lh = lane >> 4;
  const int bid = blockIdx.x;
  const int r = bid / 40, w40 = bid - r * 40, nt = w40 >> 3, x = w40 & 7;
  const int s = r * 8 + x;
  if (s >= NS256) return;
  const int m0 = s * 256, n0 = nt * 128;

  f32x4 acc[4][4];
#pragma unroll
  for (int i = 0; i < 4; i++)
#pragma unroll
    for (int j = 0; j < 4; j++) acc[i][j] = (f32x4){0.f, 0.f, 0.f, 0.f};

  // A: thread t covers row=t>>1 (0..255), k-half=(t&1)*16 (16 f32/step)
  const int arow = tid >> 1, ahalf = tid & 1;
  int rowg = m0 + arow;
  if (rowg >= N_NODES) rowg = N_NODES - 1;  // clamp; masked via gid=-1 in k3
  const float* ap = feat + (size_t)rowg * IN_DIM + ahalf * 16;
  const int awr0 = ((ahalf * 2 + 0) * 256 + arow) * 8;  // shorts
  const int awr1 = ((ahalf * 2 + 1) * 256 + arow) * 8;

  // B: 512 16B-units, u = tid -> ks=u>>7, nloc=u&127 (coalesced from wcatS)
  const short* bsrc = wcatS + ((size_t)(tid >> 7) * 640 + n0 + (tid & 127)) * 8;
  const int bdst = tid * 8;

  f32x4 sa0, sa1, sa2, sa3;   // reg set A (even kt)
  f32x4 sb0, sb1, sb2, sb3;   // reg set B (odd kt)

  // prologue: issue order [A(0), B(0), A(1)] matches steady-state counts
  {
    const f32x4* p0 = (const f32x4*)(ap);
    sa0 = p0[0]; sa1 = p0[1]; sa2 = p0[2]; sa3 = p0[3];
  }
  gload_lds16(bsrc, &Bs[0][bdst]);
  {
    const f32x4* p1 = (const f32x4*)(ap + 32);
    sb0 = p1[0]; sb1 = p1[1]; sb2 = p1[2]; sb3 = p1[3];
  }

#define K1_STEP(KT, R0, R1, R2, R3, VM, DO_B, DO_A)                            \
  {                                                                            \
    const int cur = (KT) & 1;                                                  \
    bf16x8 w0, w1;                                                             \
    _Pragma("unroll")                                                          \
    for (int q = 0; q < 4; q++) {                                              \
      w0[q] = f2bf_hw(R0[q]); w0[q + 4] = f2bf_hw(R1[q]);                      \
      w1[q] = f2bf_hw(R2[q]); w1[q + 4] = f2bf_hw(R3[q]);                      \
    }                                                                          \
    *(bf16x8*)(&As[awr0]) = w0;                                                \
    *(bf16x8*)(&As[awr1]) = w1;                                                \
    if (DO_B)                                                                  \
      gload_lds16(bsrc + (size_t)((KT) + 1) * 20480, &Bs[cur ^ 1][bdst]);      \
    if (DO_A) {                                                                \
      const f32x4* pp = (const f32x4*)(ap + ((KT) + 2) * 32);                  \
      R0 = pp[0]; R1 = pp[1]; R2 = pp[2]; R3 = pp[3];                          \
    }                                                                          \
    asm volatile("s_waitcnt vmcnt(" #VM ") lgkmcnt(0)" ::: "memory");          \
    __builtin_amdgcn_s_barrier();                                              \
    __builtin_amdgcn_sched_barrier(0);                                         \
    bf16x8 a[4], b[4];                                                         \
    _Pragma("unroll")                                                          \
    for (int i = 0; i < 4; i++)                                                \
      a[i] = *(const bf16x8*)(&As[(lh * 256 + mw * 64 + i * 16 + l16) * 8]);   \
    _Pragma("unroll")                                                          \
    for (int j = 0; j < 4; j++)                                                \
      b[j] = *(const bf16x8*)(&Bs[cur][(lh * 128 + nw * 64 + j * 16 + l16) * 8]);\
    _Pragma("unroll")                                                          \
    for (int i = 0; i < 4; i++)                                                \
      _Pragma("unroll")                                                        \
      for (int j = 0; j < 4; j++) acc[i][j] = mfma16(a[i], b[j], acc[i][j]);   \
    __builtin_amdgcn_s_barrier();                                              \
  }

  for (int kt = 0; kt < 62; kt += 2) {
    K1_STEP(kt,     sa0, sa1, sa2, sa3, 9, 1, 1)   // steady: B(kt)+A(kt+1)+B(kt+1)+A(kt+2)=10 -> drain B(kt)
    K1_STEP(kt + 1, sb0, sb1, sb2, sb3, 9, 1, 1)
  }
  K1_STEP(62, sa0, sa1, sa2, sa3, 5, 1, 0)         // B(62)+A(63)+B(63)=6 -> drain B(62)
  K1_STEP(63, sb0, sb1, sb2, sb3, 0, 0, 0)         // drain B(63)
#undef K1_STEP

  if (nt < 4) {
    float bias[4];
#pragma unroll
    for (int j = 0; j < 4; j++) bias[j] = b1[n0 + nw * 64 + j * 16 + l16];
#pragma unroll
    for (int j = 0; j < 4; j++) {
      const int col = n0 + nw * 64 + j * 16 + l16;
#pragma unroll
      for (int i = 0; i < 4; i++) {
        const int row = m0 + mw * 64 + i * 16 + lh * 4;
#pragma unroll
        for (int rr = 0; rr < 4; rr++) {
          float v = acc[i][j][rr] + bias[j];
          v = v > 0.f ? v : 0.f;
          h1[(size_t)(row + rr) * HID + col] = f2bf(v);
        }
      }
    }
  } else {
    float bias[4];
#pragma unroll
    for (int j = 0; j < 4; j++) {
      int c = nw * 64 + j * 16 + l16;
      bias[j] = b3[c] + bj[c];
    }
#pragma unroll
    for (int j = 0; j < 4; j++) {
      const int c = nw * 64 + j * 16 + l16;
#pragma unroll
      for (int i = 0; i < 4; i++) {
        const int row = m0 + mw * 64 + i * 16 + lh * 4;
#pragma unroll
        for (int rr = 0; rr < 4; rr++)
          jmp[(size_t)(row + rr) * OUTD + c] = f2bf(acc[i][j][rr] + bias[j]);
      }
    }
  }
}

// ---- K2: 256x128 tile, 8 waves; A and B both dbuf gload_lds, counted vmcnt.
// Grid: bid = r*32 + nt*8 + x (4 nt-siblings per XCD share the h1 tile in L2).
__global__ __launch_bounds__(512, 4) void k2(
    const short* __restrict__ h1, const short* __restrict__ w2tS,
    const float* __restrict__ b2, short* __restrict__ h2) {
  __shared__ __align__(16) short Asb[2][4 * 256 * 8];  // dbuf 16KB each
  __shared__ __align__(16) short Bsb[2][4 * 128 * 8];  // dbuf 8KB each
  const int tid = threadIdx.x;
  const int lane = tid & 63, w = tid >> 6;
  const int mw = w >> 1, nw = w & 1;
  const int l16 = lane & 15, lh = lane >> 4;
  const int bid = blockIdx.x;
  const int r = bid >> 5, w32 = bid & 31, nt = w32 >> 3, x = w32 & 7;
  const int s = r * 8 + x;
  if (s >= NS256) return;
  const int m0 = s * 256, n0 = nt * 128;

  f32x4 acc[4][4];
#pragma unroll
  for (int i = 0; i < 4; i++)
#pragma unroll
    for (int j = 0; j < 4; j++) acc[i][j] = (f32x4){0.f, 0.f, 0.f, 0.f};

  // A: 1024 units (u = i*512+tid): ks=u>>8, row=u&255 (per-lane row src)
  const short* asrc[2];
  int adst[2];
#pragma unroll
  for (int i = 0; i < 2; i++) {
    int u = i * 512 + tid;
    asrc[i] = h1 + (size_t)(m0 + (u & 255)) * HID + (u >> 8) * 8;
    adst[i] = u * 8;
  }
  // B: 512 units: ks=tid>>7, nloc=tid&127 (coalesced from w2tS)
  const short* bsrc = w2tS + ((size_t)(tid >> 7) * 512 + n0 + (tid & 127)) * 8;
  const int bdst = tid * 8;

  // prologue: [A(0) x2, B(0)]
  gload_lds16(asrc[0], &Asb[0][adst[0]]);
  gload_lds16(asrc[1], &Asb[0][adst[1]]);
  gload_lds16(bsrc, &Bsb[0][bdst]);

#define K2_STEP(KT, VM, DO_S)                                                  \
  {                                                                            \
    const int cur = (KT) & 1;                                                  \
    if (DO_S) {                                                                \
      gload_lds16(asrc[0] + ((KT) + 1) * 32, &Asb[cur ^ 1][adst[0]]);          \
      gload_lds16(asrc[1] + ((KT) + 1) * 32, &Asb[cur ^ 1][adst[1]]);          \
      gload_lds16(bsrc + (size_t)((KT) + 1) * 16384, &Bsb[cur ^ 1][bdst]);     \
    }                                                                          \
    asm volatile("s_waitcnt vmcnt(" #VM ")" ::: "memory");                     \
    __builtin_amdgcn_s_barrier();                                              \
    __builtin_amdgcn_sched_barrier(0);                                         \
    bf16x8 a[4], b[4];                                                         \
    _Pragma("unroll")                                                          \
    for (int i = 0; i < 4; i++)                                                \
      a[i] = *(const bf16x8*)(&Asb[cur][(lh * 256 + mw * 64 + i * 16 + l16) * 8]);\
    _Pragma("unroll")                                                          \
    for (int j = 0; j < 4; j++)                                                \
      b[j] = *(const bf16x8*)(&Bsb[cur][(lh * 128 + nw * 64 + j * 16 + l16) * 8]);\
    _Pragma("unroll")                                                          \
    for (int i = 0; i < 4; i++)                                                \
      _Pragma("unroll")                                                        \
      for (int j = 0; j < 4; j++) acc[i][j] = mfma16(a[i], b[j], acc[i][j]);   \
    __builtin_amdgcn_s_barrier();                                              \
  }

  for (int kt = 0; kt < 15; ++kt) {
    K2_STEP(kt, 3, 1)   // outstanding: [A,B](kt)=3 + [A,B](kt+1)=3 -> drain 3 oldest
  }
  K2_STEP(15, 0, 0)
#undef K2_STEP

  float bias[4];
#pragma unroll
  for (int j = 0; j < 4; j++) bias[j] = b2[n0 + nw * 64 + j * 16 + l16];
#pragma unroll
  for (int j = 0; j < 4; j++) {
    const int col = n0 + nw * 64 + j * 16 + l16;
#pragma unroll
    for (int i = 0; i < 4; i++) {
      const int row = m0 + mw * 64 + i * 16 + lh * 4;
#pragma unroll
      for (int rr = 0; rr < 4; rr++) {
        float v = acc[i][j][rr] + bias[j];
        v = v > 0.f ? v : 0.f;
        h2[(size_t)(row + rr) * HID + col] = f2bf(v);
      }
    }
  }
}

// ---------------- K3: l_enc = h2@W3^T + jump; res = l_enc@g_enc^T; JS loss ----
__global__ __launch_bounds__(256, 2) void k3(
    const short* __restrict__ h2, const short* __restrict__ w3t,
    const short* __restrict__ jmp, const short* __restrict__ genc,
    const int* __restrict__ gid, float* __restrict__ partials) {
  __shared__ __align__(16) short As[128 * 32];
  __shared__ __align__(16) short Bs[128 * 32];
  __shared__ __align__(16) short Ll[128 * 128];  // l_enc, XOR-swizzled rows
  __shared__ int gids[128];
  __shared__ float sred[8];
  const int mt = blockIdx.x;
  const int m0 = mt * 128;
  const int tid = threadIdx.x;
  const int lane = tid & 63, wid = tid >> 6;
  const int wr = wid >> 1, wc = wid & 1;
  const int l16 = lane & 15, lh = lane >> 4;

  if (tid < 128) {
    int r = m0 + tid;
    gids[tid] = (r < N_NODES) ? gid[r] : -1;
  }

  f32x4 acc[4][4];
#pragma unroll
  for (int i = 0; i < 4; i++)
#pragma unroll
    for (int j = 0; j < 4; j++) acc[i][j] = (f32x4){0.f, 0.f, 0.f, 0.f};

  const short* ap0 = h2 + (size_t)(m0 + (tid >> 2)) * HID + (tid & 3) * 8;
  const short* ap1 = ap0 + (size_t)64 * HID;
  const short* bp0 = w3t + (size_t)(tid >> 2) * HID + (tid & 3) * 8;
  const short* bp1 = bp0 + (size_t)64 * HID;

  for (int kt = 0; kt < HID / 32; ++kt) {
    __syncthreads();
    gload_lds16(ap0 + kt * 32, &As[tid * 8]);
    gload_lds16(ap1 + kt * 32, &As[tid * 8 + 2048]);
    gload_lds16(bp0 + kt * 32, &Bs[tid * 8]);
    gload_lds16(bp1 + kt * 32, &Bs[tid * 8 + 2048]);
    __syncthreads();
    bf16x8 a[4], b[4];
#pragma unroll
    for (int i = 0; i < 4; i++)
      a[i] = *(const bf16x8*)(&As[(wr * 64 + i * 16 + l16) * 32 + lh * 8]);
#pragma unroll
    for (int j = 0; j < 4; j++)
      b[j] = *(const bf16x8*)(&Bs[(wc * 64 + j * 16 + l16) * 32 + lh * 8]);
#pragma unroll
    for (int i = 0; i < 4; i++)
#pragma unroll
      for (int j = 0; j < 4; j++) acc[i][j] = mfma16(a[i], b[j], acc[i][j]);
  }

  // epilogue: l_enc = acc + jump (jump already holds b3+bj) -> Ll (swizzled)
#pragma unroll
  for (int j = 0; j < 4; j++) {
    const int col = wc * 64 + j * 16 + l16;
#pragma unroll
    for (int i = 0; i < 4; i++) {
      const int rowb = wr * 64 + i * 16 + lh * 4;
#pragma unroll
      for (int r = 0; r < 4; r++) {
        const int row = rowb + r;
        float v = acc[i][j][r] + bf2f(jmp[(size_t)(m0 + row) * OUTD + col]);
        unsigned byte = (unsigned)row * 256u +
                        (((unsigned)col * 2u) ^ (((unsigned)(row & 7)) << 4));
        *(short*)((char*)Ll + byte) = f2bf(v);
      }
    }
  }
  __syncthreads();

  int myg[4][4];
#pragma unroll
  for (int i = 0; i < 4; i++)
#pragma unroll
    for (int r = 0; r < 4; r++) myg[i][r] = gids[wr * 64 + i * 16 + lh * 4 + r];

  float pacc = 0.f, nacc = 0.f;
  for (int nc = 0; nc < 4; ++nc) {
    f32x4 a2[4][4];
#pragma unroll
    for (int i = 0; i < 4; i++)
#pragma unroll
      for (int j = 0; j < 4; j++) a2[i][j] = (f32x4){0.f, 0.f, 0.f, 0.f};
#pragma unroll
    for (int ks = 0; ks < 4; ++ks) {
      bf16x8 af[4], bg[4];
#pragma unroll
      for (int i = 0; i < 4; i++) {
        const int row = wr * 64 + i * 16 + l16;
        unsigned byte = (unsigned)row * 256u +
                        (((unsigned)(ks * 64 + lh * 16)) ^ (((unsigned)(row & 7)) << 4));
        af[i] = *(const bf16x8*)((const char*)Ll + byte);
      }
#pragma unroll
      for (int j = 0; j < 4; j++) {
        const int g = nc * 128 + wc * 64 + j * 16 + l16;
        bg[j] = *(const bf16x8*)(genc + (size_t)g * OUTD + ks * 32 + lh * 8);
      }
#pragma unroll
      for (int i = 0; i < 4; i++)
#pragma unroll
        for (int j = 0; j < 4; j++) a2[i][j] = mfma16(af[i], bg[j], a2[i][j]);
    }
#pragma unroll
    for (int j = 0; j < 4; j++) {
      const int g = nc * 128 + wc * 64 + j * 16 + l16;
#pragma unroll
      for (int i = 0; i < 4; i++) {
#pragma unroll
        for (int r = 0; r < 4; r++) {
          float rv = a2[i][j][r];
          int gr = myg[i][r];
          float t = __expf(-fabsf(rv));
          float lg = __logf(1.f + t);
          if (gr == g)
            pacc += LOG2F_ - (fmaxf(-rv, 0.f) + lg);
          else if (gr >= 0)
            nacc += (fmaxf(rv, 0.f) + lg) - LOG2F_;
        }
      }
    }
  }

#pragma unroll
  for (int o = 32; o; o >>= 1) {
    pacc += __shfl_down(pacc, o);
    nacc += __shfl_down(nacc, o);
  }
  if (lane == 0) { sred[wid] = pacc; sred[4 + wid] = nacc; }
  __syncthreads();
  if (tid == 0) {
    partials[2 * mt] = sred[0] + sred[1] + sred[2] + sred[3];
    partials[2 * mt + 1] = sred[4] + sred[5] + sred[6] + sred[7];
  }
}

// ---------------- K4: deterministic final reduction ---------------------------
__global__ void k4(const float* __restrict__ partials, float* __restrict__ out) {
  const int tid = threadIdx.x;
  float p = 0.f, n = 0.f;
  for (int i = tid; i < MT; i += 256) {
    p += partials[2 * i];
    n += partials[2 * i + 1];
  }
#pragma unroll
  for (int o = 32; o; o >>= 1) {
    p += __shfl_down(p, o);
    n += __shfl_down(n, o);
  }
  __shared__ float sp[4], sn[4];
  const int wid = tid >> 6, lane = tid & 63;
  if (lane == 0) { sp[wid] = p; sn[wid] = n; }
  __syncthreads();
  if (tid == 0) {
    float P = sp[0] + sp[1] + sp[2] + sp[3];
    float Nn = sn[0] + sn[1] + sn[2] + sn[3];
    out[0] = Nn / (100000.0f * 511.0f) - P / 100000.0f;
  }
}

extern "C" void kernel_launch(void* const* d_in, const int* in_sizes, int n_in,
                              void* d_out, int out_size, void* d_ws, size_t ws_size,
                              hipStream_t stream) {
  const float* feat = (const float*)d_in[0];
  const float* genc_f = (const float*)d_in[1];
  const int* gid = (const int*)d_in[2];
  const float* W1 = (const float*)d_in[3];
  const float* b1 = (const float*)d_in[4];
  const float* W2 = (const float*)d_in[5];
  const float* b2 = (const float*)d_in[6];
  const float* W3 = (const float*)d_in[7];
  const float* b3 = (const float*)d_in[8];
  const float* Wj = (const float*)d_in[9];
  const float* bj = (const float*)d_in[10];
  float* out = (float*)d_out;

  char* ws = (char*)d_ws;
  float* partials = (float*)ws;                       // 782*2 f32
  short* wcatS = (short*)(ws + 8192);                 // [256][640][8] k-slot
  short* w2tS = wcatS + (size_t)640 * 2048;           // [64][512][8] k-slot
  short* w3t = w2tS + (size_t)512 * 512;              // [128][512] row-major
  short* gencb = w3t + (size_t)128 * 512;             // [512][128] row-major
  short* h1 = gencb + (size_t)512 * 128;              // [MPAD][512]
  short* h2 = h1 + (size_t)MPAD * 512;                // [MPAD][512]
  short* jmp = h2 + (size_t)MPAD * 512;               // [MPAD][128]

  kprep<<<6656, 256, 0, stream>>>(W1, Wj, W2, W3, genc_f, wcatS, w2tS, w3t, gencb);
  k1<<<49 * 40, 512, 0, stream>>>(feat, wcatS, b1, b3, bj, h1, jmp);
  k2<<<49 * 32, 512, 0, stream>>>(h1, w2tS, b2, h2);
  k3<<<MT, 256, 0, stream>>>(h2, w3t, jmp, gencb, gid, partials);
  k4<<<1, 256, 0, stream>>>(partials, out);
}

// Round 14
// 603.538 us; speedup vs baseline: 1.8707x; 1.8707x over previous
//
#include <hip/hip_runtime.h>
#include <hip/hip_bf16.h>
#include <stdint.h>

#define N_NODES 100000
#define MT      782          // 128-row tiles (k3)
#define NS256   391          // 256-row stripes (k1,k2)
#define MPAD    (MT*128)     // 100096 = 391*256
#define IN_DIM  2048
#define HID     512
#define OUTD    128
#define NG      512
#define NPAD    768          // k1 padded N (3 x 256)
#define LOG2F_  0.69314718055994531f

typedef __attribute__((ext_vector_type(4))) float f32x4;
typedef __attribute__((ext_vector_type(8))) short bf16x8;

typedef const __attribute__((address_space(1))) unsigned int gas_u32;
typedef __attribute__((address_space(3))) unsigned int las_u32;

__device__ __forceinline__ void gload_lds16(const void* g, void* lds) {
  __builtin_amdgcn_global_load_lds((gas_u32*)g, (las_u32*)lds, 16, 0, 0);
}

__device__ __forceinline__ short f2bf(float f) {   // manual RNE
  unsigned u = __builtin_bit_cast(unsigned, f);
  u = (u + 0x7fffu + ((u >> 16) & 1u)) >> 16;
  return (short)u;
}
__device__ __forceinline__ short f2bf_hw(float f) {
  __hip_bfloat16 h = __float2bfloat16(f);
  return __builtin_bit_cast(short, h);
}
__device__ __forceinline__ float bf2f(short s) {
  unsigned u = ((unsigned)(unsigned short)s) << 16;
  return __builtin_bit_cast(float, u);
}

__device__ __forceinline__ f32x4 mfma16(bf16x8 a, bf16x8 b, f32x4 c) {
  return __builtin_amdgcn_mfma_f32_16x16x32_bf16(a, b, c, 0, 0, 0);
}

// ---------------- prep ---------------------------------------------------------
// wcatS: k-slot [k/8][NPAD][e] ([W1|Wj] cols 0..639, zero-pad 640..767).
// w2tS : k-slot [k/8][512][e].  w3t: row-major [n][k].  gencb: row-major [g][k].
__global__ void kprep(const float* __restrict__ W1, const float* __restrict__ Wj,
                      const float* __restrict__ W2, const float* __restrict__ W3,
                      const float* __restrict__ ge,
                      short* __restrict__ wcatS, short* __restrict__ w2tS,
                      short* __restrict__ w3t, short* __restrict__ gencb) {
  const int S1 = 256 * NPAD * 8, S2 = 64 * 512 * 8, S3 = 128 * 512, S4 = 512 * 128;
  int t = blockIdx.x * 256 + threadIdx.x;
  if (t < S1) {
    int e = t & 7, rest = t >> 3;
    int n = rest % NPAD, kb = rest / NPAD;
    int k = kb * 8 + e;
    float v = 0.f;
    if (n < 512) v = W1[(size_t)k * 512 + n];
    else if (n < 640) v = Wj[(size_t)k * 128 + (n - 512)];
    wcatS[t] = f2bf(v);
  } else {
    t -= S1;
    if (t < S2) {
      int e = t & 7, rest = t >> 3;
      int n = rest & 511, kb = rest >> 9;
      int k = kb * 8 + e;
      w2tS[t] = f2bf(W2[(size_t)k * 512 + n]);
    } else {
      t -= S2;
      if (t < S3) {
        int n = t >> 9, k = t & 511;
        w3t[t] = f2bf(W3[(size_t)k * 128 + n]);
      } else {
        t -= S3;
        if (t < S4) gencb[t] = f2bf(ge[t]);
      }
    }
  }
}

// ---- K1: 256x256 tile, BK=64, 512 thr / 8 waves (2Mx4N, wave 128x64, acc 128).
// T3-minimum loop: ONE barrier + ONE vmcnt(0) per K-tile, placed AFTER the
// 64-MFMA cluster (staging latency hides under ~2500cyc compute; m230/m248).
// A (f32) reg-staged: 8x dwordx4 issued at top for tile t+1, cvt + XOR-swizzled
// ds_write after compute. B via gload_lds from k-slot wcatS (linear dest).
// Grid: bid = r*24 + nt*8 + x, stripe s = r*8+x -> 3 nt-siblings on same XCD.
__global__ __launch_bounds__(512, 1) void k1(
    const float* __restrict__ feat, const short* __restrict__ wcatS,
    const float* __restrict__ b1, const float* __restrict__ b3,
    const float* __restrict__ bj,
    short* __restrict__ h1, short* __restrict__ jmp) {
  // LDS: A dbuf 2x32KB @0 ([row(256)][octswz(8)][8bf16], byte=row*128+oct'*16),
  //      B dbuf 2x32KB @65536 ([oct(8)][n(256)][8bf16], linear for gload_lds)
  __shared__ __align__(16) char L[131072];
  const int tid = threadIdx.x;
  const int lane = tid & 63, w = tid >> 6;
  const int l16 = lane & 15, lh = lane >> 4;
  const int mw = w >> 2, nw = w & 3;         // 2M x 4N waves; wave tile 128x64
  const int bid = blockIdx.x;
  const int r = bid / 24, w24 = bid - r * 24, nt = w24 >> 3, x = w24 & 7;
  const int s = r * 8 + x;
  if (s >= NS256) return;
  const int m0 = s * 256;
  const int n0 = nt * 256;

  f32x4 acc[8][4];
#pragma unroll
  for (int m = 0; m < 8; m++)
#pragma unroll
    for (int j = 0; j < 4; j++) acc[m][j] = (f32x4){0.f, 0.f, 0.f, 0.f};

  // ---- A staging geometry: unit v = j*512+tid -> oct=tid&7, row=tid>>3 + j*64
  const int aoct = tid & 7;
  const int arow0 = tid >> 3;                // + j*64
  const int aoctw = aoct ^ (arow0 & 7);      // write swizzle (j*64 == 0 mod 8)
  const float* asrc[4];
#pragma unroll
  for (int j = 0; j < 4; j++) {
    int rowg = m0 + arow0 + j * 64;
    if (rowg >= N_NODES) rowg = N_NODES - 1;  // clamp; masked via gid=-1 in k3
    asrc[j] = feat + (size_t)rowg * IN_DIM + aoct * 8;
  }
  int awr[4];
#pragma unroll
  for (int j = 0; j < 4; j++) awr[j] = (arow0 + j * 64) * 128 + aoctw * 16;

  // ---- B staging geometry: unit u = i*512+tid -> oct=u>>8, nloc=u&255
  const short* bsrc[4];
  int bdst[4];
#pragma unroll
  for (int i = 0; i < 4; i++) {
    int u = i * 512 + tid;
    int oct = u >> 8, nloc = u & 255;
    bsrc[i] = wcatS + ((size_t)oct * NPAD + n0 + nloc) * 8;
    bdst[i] = 65536 + u * 16;
  }
  const size_t bkstride = (size_t)8 * NPAD * 8;  // shorts per K-tile (8 planes)

  // ---- frag read bases
  int aoffs[2], boffs[2];
#pragma unroll
  for (int ks = 0; ks < 2; ks++) {
    aoffs[ks] = (mw * 128 + l16) * 128 + ((ks * 4 + lh) ^ (l16 & 7)) * 16;
    boffs[ks] = 65536 + ((ks * 4 + lh) * 256 + nw * 64 + l16) * 16;
  }

  f32x4 lo[4], hi[4];

  // ---- prologue: stage tile 0 into buffer 0
#pragma unroll
  for (int i = 0; i < 4; i++) gload_lds16(bsrc[i], L + bdst[i]);
#pragma unroll
  for (int j = 0; j < 4; j++) {
    lo[j] = *(const f32x4*)(asrc[j]);
    hi[j] = *(const f32x4*)(asrc[j] + 4);
  }
  asm volatile("s_waitcnt vmcnt(0)" ::: "memory");
#pragma unroll
  for (int j = 0; j < 4; j++) {
    bf16x8 v;
#pragma unroll
    for (int q = 0; q < 4; q++) { v[q] = f2bf_hw(lo[j][q]); v[q + 4] = f2bf_hw(hi[j][q]); }
    *(bf16x8*)(L + awr[j]) = v;
  }
  asm volatile("s_waitcnt lgkmcnt(0)\ns_barrier" ::: "memory");

  for (int kt = 0; kt < 32; ++kt) {
    const int c = kt & 1, nc = c ^ 1;
    // stage issue for tile kt+1 (covered by the compute below)
    if (kt < 31) {
#pragma unroll
      for (int i = 0; i < 4; i++)
        gload_lds16(bsrc[i] + (size_t)(kt + 1) * bkstride, L + nc * 32768 + bdst[i]);
#pragma unroll
      for (int j = 0; j < 4; j++) {
        lo[j] = *(const f32x4*)(asrc[j] + (kt + 1) * 64);
        hi[j] = *(const f32x4*)(asrc[j] + (kt + 1) * 64 + 4);
      }
    }
    // compute from buffer c
    __builtin_amdgcn_s_setprio(1);
#pragma unroll
    for (int ks = 0; ks < 2; ks++) {
      bf16x8 b[4];
#pragma unroll
      for (int j = 0; j < 4; j++)
        b[j] = *(const bf16x8*)(L + c * 32768 + boffs[ks] + j * 256);
#pragma unroll
      for (int m = 0; m < 8; m++) {
        bf16x8 a = *(const bf16x8*)(L + c * 32768 + aoffs[ks] + m * 2048);
#pragma unroll
        for (int j = 0; j < 4; j++) acc[m][j] = mfma16(a, b[j], acc[m][j]);
      }
    }
    __builtin_amdgcn_s_setprio(0);
    if (kt < 31) {
      asm volatile("s_waitcnt vmcnt(0)" ::: "memory");  // A regs + B DMA landed
#pragma unroll
      for (int j = 0; j < 4; j++) {
        bf16x8 v;
#pragma unroll
        for (int q = 0; q < 4; q++) { v[q] = f2bf_hw(lo[j][q]); v[q + 4] = f2bf_hw(hi[j][q]); }
        *(bf16x8*)(L + nc * 32768 + awr[j]) = v;
      }
      asm volatile("s_waitcnt lgkmcnt(0)\ns_barrier" ::: "memory");
    }
  }

  // ---- epilogue
#pragma unroll
  for (int j = 0; j < 4; j++) {
    const int col = n0 + nw * 64 + j * 16 + l16;
    if (col < 512) {
      const float bias = b1[col];
#pragma unroll
      for (int m = 0; m < 8; m++) {
        const int row = m0 + mw * 128 + m * 16 + lh * 4;
#pragma unroll
        for (int rr = 0; rr < 4; rr++) {
          float v = acc[m][j][rr] + bias;
          v = v > 0.f ? v : 0.f;
          h1[(size_t)(row + rr) * HID + col] = f2bf(v);
        }
      }
    } else if (col < 640) {
      const int cj = col - 512;
      const float bias = b3[cj] + bj[cj];
#pragma unroll
      for (int m = 0; m < 8; m++) {
        const int row = m0 + mw * 128 + m * 16 + lh * 4;
#pragma unroll
        for (int rr = 0; rr < 4; rr++)
          jmp[(size_t)(row + rr) * OUTD + cj] = f2bf(acc[m][j][rr] + bias);
      }
    }
  }
}

// ---- K2: same 256x256/BK=64 skeleton, bf16 A from h1 (row-major), K=512.
// Grid: bid = r*16 + nt*8 + x (2 nt-siblings per XCD share the h1 stripe).
__global__ __launch_bounds__(512, 1) void k2(
    const short* __restrict__ h1, const short* __restrict__ w2tS,
    const float* __restrict__ b2, short* __restrict__ h2) {
  __shared__ __align__(16) char L[131072];
  const int tid = threadIdx.x;
  const int lane = tid & 63, w = tid >> 6;
  const int l16 = lane & 15, lh = lane >> 4;
  const int mw = w >> 2, nw = w & 3;
  const int bid = blockIdx.x;
  const int r = bid >> 4, w16 = bid & 15, nt = w16 >> 3, x = w16 & 7;
  const int s = r * 8 + x;
  if (s >= NS256) return;
  const int m0 = s * 256, n0 = nt * 256;

  f32x4 acc[8][4];
#pragma unroll
  for (int m = 0; m < 8; m++)
#pragma unroll
    for (int j = 0; j < 4; j++) acc[m][j] = (f32x4){0.f, 0.f, 0.f, 0.f};

  const int aoct = tid & 7;
  const int arow0 = tid >> 3;
  const int aoctw = aoct ^ (arow0 & 7);
  const short* asrc[4];
  int awr[4];
#pragma unroll
  for (int j = 0; j < 4; j++) {
    asrc[j] = h1 + (size_t)(m0 + arow0 + j * 64) * HID + aoct * 8;
    awr[j] = (arow0 + j * 64) * 128 + aoctw * 16;
  }

  const short* bsrc[4];
  int bdst[4];
#pragma unroll
  for (int i = 0; i < 4; i++) {
    int u = i * 512 + tid;
    int oct = u >> 8, nloc = u & 255;
    bsrc[i] = w2tS + ((size_t)oct * 512 + n0 + nloc) * 8;
    bdst[i] = 65536 + u * 16;
  }
  const size_t bkstride = (size_t)8 * 512 * 8;

  int aoffs[2], boffs[2];
#pragma unroll
  for (int ks = 0; ks < 2; ks++) {
    aoffs[ks] = (mw * 128 + l16) * 128 + ((ks * 4 + lh) ^ (l16 & 7)) * 16;
    boffs[ks] = 65536 + ((ks * 4 + lh) * 256 + nw * 64 + l16) * 16;
  }

  bf16x8 ar[4];

  // prologue: tile 0 -> buffer 0
#pragma unroll
  for (int i = 0; i < 4; i++) gload_lds16(bsrc[i], L + bdst[i]);
#pragma unroll
  for (int j = 0; j < 4; j++) ar[j] = *(const bf16x8*)(asrc[j]);
  asm volatile("s_waitcnt vmcnt(0)" ::: "memory");
#pragma unroll
  for (int j = 0; j < 4; j++) *(bf16x8*)(L + awr[j]) = ar[j];
  asm volatile("s_waitcnt lgkmcnt(0)\ns_barrier" ::: "memory");

  for (int kt = 0; kt < 8; ++kt) {
    const int c = kt & 1, nc = c ^ 1;
    if (kt < 7) {
#pragma unroll
      for (int i = 0; i < 4; i++)
        gload_lds16(bsrc[i] + (size_t)(kt + 1) * bkstride, L + nc * 32768 + bdst[i]);
#pragma unroll
      for (int j = 0; j < 4; j++) ar[j] = *(const bf16x8*)(asrc[j] + (kt + 1) * 64);
    }
    __builtin_amdgcn_s_setprio(1);
#pragma unroll
    for (int ks = 0; ks < 2; ks++) {
      bf16x8 b[4];
#pragma unroll
      for (int j = 0; j < 4; j++)
        b[j] = *(const bf16x8*)(L + c * 32768 + boffs[ks] + j * 256);
#pragma unroll
      for (int m = 0; m < 8; m++) {
        bf16x8 a = *(const bf16x8*)(L + c * 32768 + aoffs[ks] + m * 2048);
#pragma unroll
        for (int j = 0; j < 4; j++) acc[m][j] = mfma16(a, b[j], acc[m][j]);
      }
    }
    __builtin_amdgcn_s_setprio(0);
    if (kt < 7) {
      asm volatile("s_waitcnt vmcnt(0)" ::: "memory");
#pragma unroll
      for (int j = 0; j < 4; j++) *(bf16x8*)(L + nc * 32768 + awr[j]) = ar[j];
      asm volatile("s_waitcnt lgkmcnt(0)\ns_barrier" ::: "memory");
    }
  }

#pragma unroll
  for (int j = 0; j < 4; j++) {
    const int col = n0 + nw * 64 + j * 16 + l16;
    const float bias = b2[col];
#pragma unroll
    for (int m = 0; m < 8; m++) {
      const int row = m0 + mw * 128 + m * 16 + lh * 4;
#pragma unroll
      for (int rr = 0; rr < 4; rr++) {
        float v = acc[m][j][rr] + bias;
        v = v > 0.f ? v : 0.f;
        h2[(size_t)(row + rr) * HID + col] = f2bf(v);
      }
    }
  }
}

// ---------------- K3: l_enc = h2@W3^T + jump; res = l_enc@g_enc^T; JS loss ----
__global__ __launch_bounds__(256, 2) void k3(
    const short* __restrict__ h2, const short* __restrict__ w3t,
    const short* __restrict__ jmp, const short* __restrict__ genc,
    const int* __restrict__ gid, float* __restrict__ partials) {
  __shared__ __align__(16) short As[128 * 32];
  __shared__ __align__(16) short Bs[128 * 32];
  __shared__ __align__(16) short Ll[128 * 128];  // l_enc, XOR-swizzled rows
  __shared__ int gids[128];
  __shared__ float sred[8];
  const int mt = blockIdx.x;
  const int m0 = mt * 128;
  const int tid = threadIdx.x;
  const int lane = tid & 63, wid = tid >> 6;
  const int wr = wid >> 1, wc = wid & 1;
  const int l16 = lane & 15, lh = lane >> 4;

  if (tid < 128) {
    int r = m0 + tid;
    gids[tid] = (r < N_NODES) ? gid[r] : -1;
  }

  f32x4 acc[4][4];
#pragma unroll
  for (int i = 0; i < 4; i++)
#pragma unroll
    for (int j = 0; j < 4; j++) acc[i][j] = (f32x4){0.f, 0.f, 0.f, 0.f};

  const short* ap0 = h2 + (size_t)(m0 + (tid >> 2)) * HID + (tid & 3) * 8;
  const short* ap1 = ap0 + (size_t)64 * HID;
  const short* bp0 = w3t + (size_t)(tid >> 2) * HID + (tid & 3) * 8;
  const short* bp1 = bp0 + (size_t)64 * HID;

  for (int kt = 0; kt < HID / 32; ++kt) {
    __syncthreads();
    gload_lds16(ap0 + kt * 32, &As[tid * 8]);
    gload_lds16(ap1 + kt * 32, &As[tid * 8 + 2048]);
    gload_lds16(bp0 + kt * 32, &Bs[tid * 8]);
    gload_lds16(bp1 + kt * 32, &Bs[tid * 8 + 2048]);
    __syncthreads();
    bf16x8 a[4], b[4];
#pragma unroll
    for (int i = 0; i < 4; i++)
      a[i] = *(const bf16x8*)(&As[(wr * 64 + i * 16 + l16) * 32 + lh * 8]);
#pragma unroll
    for (int j = 0; j < 4; j++)
      b[j] = *(const bf16x8*)(&Bs[(wc * 64 + j * 16 + l16) * 32 + lh * 8]);
#pragma unroll
    for (int i = 0; i < 4; i++)
#pragma unroll
      for (int j = 0; j < 4; j++) acc[i][j] = mfma16(a[i], b[j], acc[i][j]);
  }

  // epilogue: l_enc = acc + jump (jump already holds b3+bj) -> Ll (swizzled)
#pragma unroll
  for (int j = 0; j < 4; j++) {
    const int col = wc * 64 + j * 16 + l16;
#pragma unroll
    for (int i = 0; i < 4; i++) {
      const int rowb = wr * 64 + i * 16 + lh * 4;
#pragma unroll
      for (int r = 0; r < 4; r++) {
        const int row = rowb + r;
        float v = acc[i][j][r] + bf2f(jmp[(size_t)(m0 + row) * OUTD + col]);
        unsigned byte = (unsigned)row * 256u +
                        (((unsigned)col * 2u) ^ (((unsigned)(row & 7)) << 4));
        *(short*)((char*)Ll + byte) = f2bf(v);
      }
    }
  }
  __syncthreads();

  int myg[4][4];
#pragma unroll
  for (int i = 0; i < 4; i++)
#pragma unroll
    for (int r = 0; r < 4; r++) myg[i][r] = gids[wr * 64 + i * 16 + lh * 4 + r];

  float pacc = 0.f, nacc = 0.f;
  for (int nc = 0; nc < 4; ++nc) {
    f32x4 a2[4][4];
#pragma unroll
    for (int i = 0; i < 4; i++)
#pragma unroll
      for (int j = 0; j < 4; j++) a2[i][j] = (f32x4){0.f, 0.f, 0.f, 0.f};
#pragma unroll
    for (int ks = 0; ks < 4; ++ks) {
      bf16x8 af[4], bg[4];
#pragma unroll
      for (int i = 0; i < 4; i++) {
        const int row = wr * 64 + i * 16 + l16;
        unsigned byte = (unsigned)row * 256u +
                        (((unsigned)(ks * 64 + lh * 16)) ^ (((unsigned)(row & 7)) << 4));
        af[i] = *(const bf16x8*)((const char*)Ll + byte);
      }
#pragma unroll
      for (int j = 0; j < 4; j++) {
        const int g = nc * 128 + wc * 64 + j * 16 + l16;
        bg[j] = *(const bf16x8*)(genc + (size_t)g * OUTD + ks * 32 + lh * 8);
      }
#pragma unroll
      for (int i = 0; i < 4; i++)
#pragma unroll
        for (int j = 0; j < 4; j++) a2[i][j] = mfma16(af[i], bg[j], a2[i][j]);
    }
#pragma unroll
    for (int j = 0; j < 4; j++) {
      const int g = nc * 128 + wc * 64 + j * 16 + l16;
#pragma unroll
      for (int i = 0; i < 4; i++) {
#pragma unroll
        for (int r = 0; r < 4; r++) {
          float rv = a2[i][j][r];
          int gr = myg[i][r];
          float t = __expf(-fabsf(rv));
          float lg = __logf(1.f + t);
          if (gr == g)
            pacc += LOG2F_ - (fmaxf(-rv, 0.f) + lg);
          else if (gr >= 0)
            nacc += (fmaxf(rv, 0.f) + lg) - LOG2F_;
        }
      }
    }
  }

#pragma unroll
  for (int o = 32; o; o >>= 1) {
    pacc += __shfl_down(pacc, o);
    nacc += __shfl_down(nacc, o);
  }
  if (lane == 0) { sred[wid] = pacc; sred[4 + wid] = nacc; }
  __syncthreads();
  if (tid == 0) {
    partials[2 * mt] = sred[0] + sred[1] + sred[2] + sred[3];
    partials[2 * mt + 1] = sred[4] + sred[5] + sred[6] + sred[7];
  }
}

// ---------------- K4: deterministic final reduction ---------------------------
__global__ void k4(const float* __restrict__ partials, float* __restrict__ out) {
  const int tid = threadIdx.x;
  float p = 0.f, n = 0.f;
  for (int i = tid; i < MT; i += 256) {
    p += partials[2 * i];
    n += partials[2 * i + 1];
  }
#pragma unroll
  for (int o = 32; o; o >>= 1) {
    p += __shfl_down(p, o);
    n += __shfl_down(n, o);
  }
  __shared__ float sp[4], sn[4];
  const int wid = tid >> 6, lane = tid & 63;
  if (lane == 0) { sp[wid] = p; sn[wid] = n; }
  __syncthreads();
  if (tid == 0) {
    float P = sp[0] + sp[1] + sp[2] + sp[3];
    float Nn = sn[0] + sn[1] + sn[2] + sn[3];
    out[0] = Nn / (100000.0f * 511.0f) - P / 100000.0f;
  }
}

extern "C" void kernel_launch(void* const* d_in, const int* in_sizes, int n_in,
                              void* d_out, int out_size, void* d_ws, size_t ws_size,
                              hipStream_t stream) {
  const float* feat = (const float*)d_in[0];
  const float* genc_f = (const float*)d_in[1];
  const int* gid = (const int*)d_in[2];
  const float* W1 = (const float*)d_in[3];
  const float* b1 = (const float*)d_in[4];
  const float* W2 = (const float*)d_in[5];
  const float* b2 = (const float*)d_in[6];
  const float* W3 = (const float*)d_in[7];
  const float* b3 = (const float*)d_in[8];
  const float* Wj = (const float*)d_in[9];
  const float* bj = (const float*)d_in[10];
  float* out = (float*)d_out;

  char* ws = (char*)d_ws;
  float* partials = (float*)ws;                       // 782*2 f32
  short* wcatS = (short*)(ws + 8192);                 // [256][768][8] k-slot
  short* w2tS = wcatS + (size_t)256 * NPAD * 8;       // [64][512][8] k-slot
  short* w3t = w2tS + (size_t)64 * 512 * 8;           // [128][512] row-major
  short* gencb = w3t + (size_t)128 * 512;             // [512][128] row-major
  short* h1 = gencb + (size_t)512 * 128;              // [MPAD][512]
  short* h2 = h1 + (size_t)MPAD * 512;                // [MPAD][512]
  short* jmp = h2 + (size_t)MPAD * 512;               // [MPAD][128]

  kprep<<<7680, 256, 0, stream>>>(W1, Wj, W2, W3, genc_f, wcatS, w2tS, w3t, gencb);
  k1<<<49 * 24, 512, 0, stream>>>(feat, wcatS, b1, b3, bj, h1, jmp);
  k2<<<49 * 16, 512, 0, stream>>>(h1, w2tS, b2, h2);
  k3<<<MT, 256, 0, stream>>>(h2, w3t, jmp, gencb, gid, partials);
  k4<<<1, 256, 0, stream>>>(partials, out);
}